// Round 10
// baseline (289.938 us; speedup 1.0000x reference)
//
#include <hip/hip_runtime.h>
#include <math.h>

#define B 4
#define C 64
#define NN 65536

typedef __attribute__((ext_vector_type(8))) short short8;
typedef __attribute__((ext_vector_type(4))) short short4b;
typedef __attribute__((ext_vector_type(4))) float f32x4;
typedef __attribute__((ext_vector_type(4))) unsigned int u32x4;

__device__ inline float bf2f(short s) {
  union { unsigned u; float f; } v; v.u = ((unsigned)(unsigned short)s) << 16; return v.f;
}
__device__ inline short f2bf(float f) {
  union { float f; unsigned u; } v; v.f = f;
  unsigned r = v.u + 0x7FFFu + ((v.u >> 16) & 1u);  // RNE
  return (short)(r >> 16);
}
// bf16 pair unpack: low half / high half of a 32-bit word.
__device__ inline float lof(unsigned u) {
  union { unsigned u; float f; } v; v.u = u << 16; return v.f;
}
__device__ inline float hif(unsigned u) {
  union { unsigned u; float f; } v; v.u = u & 0xffff0000u; return v.f;
}

// ---------------------------------------------------------------------------
// P1: pack w_qkv (first 128 rows) and w_m1 into MFMA A-frag order; zero gram2.
__global__ void k_prep1(const float* __restrict__ wqkv, const float* __restrict__ wm1,
    short* __restrict__ apk, short* __restrict__ apm, float* __restrict__ gram2) {
  for (int idx = blockIdx.x * 256 + threadIdx.x; idx < 20480; idx += 16384) {
    if (idx < 8192) {
      const int j = idx & 7, lane = (idx >> 3) & 63, mt = (idx >> 9) & 7, cc = idx >> 12;
      const int o = mt * 16 + (lane & 15), c = cc * 32 + (lane >> 4) * 8 + j;
      apk[idx] = f2bf(wqkv[o * 64 + c]);
    } else if (idx < 12288) {
      const int k = idx - 8192;
      const int j = k & 7, lane = (k >> 3) & 63, mt = (k >> 9) & 3, cc = k >> 11;
      const int o = mt * 16 + (lane & 15), c = cc * 32 + (lane >> 4) * 8 + j;
      apm[k] = f2bf(wm1[o * 64 + c]);
    } else {
      gram2[idx - 12288] = 0.f;
    }
  }
}

// ---------------------------------------------------------------------------
// FUSED xt + qk1x1 + m1_bn, latency-restructured:
//  - float4 x ingest: 4 b128 loads/thread (was 16 b32). Same lds slots.
//  - qk GEMM split into two mt-halves (peak live acc 16 regs, not 32+16),
//    phases fenced with sched_barrier(0) (no vmcnt drain).
//  - launch_bounds(256,6): reg budget 85 >= ~60 live -> 6 waves/SIMD target.
__global__ __launch_bounds__(256, 6) void k_fused(const float* __restrict__ x,
    const short* __restrict__ apk, const float* __restrict__ bqkv,
    const short* __restrict__ apm, const float* __restrict__ gamma,
    const float* __restrict__ beta, const float* __restrict__ mean,
    const float* __restrict__ var, short* __restrict__ x_t,
    short* __restrict__ qk, short* __restrict__ y_t) {
  __shared__ short lds[64 * 66];
  const int b = blockIdx.x >> 10, ntile = blockIdx.x & 1023;
  const int n0 = ntile * 64;
  const int t = threadIdx.x;
  const int wave = t >> 6, lane = t & 63;
  const int quad = lane >> 4, l15 = lane & 15;
  // Vectorized load + transpose: group g=t>>4 picks channel, s=t&15 picks
  // 4-pixel slab; 4 passes cover 64 channels. float4 = 16B/lane coalesced.
  {
    const int g = t >> 4, s = t & 15;
#pragma unroll
    for (int it = 0; it < 4; ++it) {
      const int c = it * 16 + g;
      const float4 v = *(const float4*)(x + ((size_t)(b * 64 + c)) * NN + n0 + s * 4);
      lds[(s * 4 + 0) * 66 + c] = f2bf(v.x);
      lds[(s * 4 + 1) * 66 + c] = f2bf(v.y);
      lds[(s * 4 + 2) * 66 + c] = f2bf(v.z);
      lds[(s * 4 + 3) * 66 + c] = f2bf(v.w);
    }
  }
  __syncthreads();
  // x_t write (channel-innermost), straight from the transpose buffer.
  {
    short* dst = x_t + ((size_t)(b * NN + n0)) * 64;
#pragma unroll
    for (int it = 0; it < 2; ++it) {
      const int idx = it * 256 + t;
      const int nl = idx >> 3, cb = idx & 7;
      *(short8*)(dst + (size_t)nl * 64 + cb * 8) = *(const short8*)(lds + nl * 66 + cb * 8);
    }
  }
  const int nloc = wave * 16 + l15;
  const int n = n0 + nloc;
  // qk GEMM, half A (o = 0..63).
#pragma unroll
  for (int half = 0; half < 2; ++half) {
    f32x4 acc[4];
#pragma unroll
    for (int mt = 0; mt < 4; ++mt) acc[mt] = (f32x4){0.f, 0.f, 0.f, 0.f};
#pragma unroll
    for (int cc = 0; cc < 2; ++cc) {
      const short8 bf = *(const short8*)(lds + nloc * 66 + cc * 32 + quad * 8);
#pragma unroll
      for (int mt = 0; mt < 4; ++mt) {
        const short8 af = *(const short8*)(apk + ((cc * 8 + half * 4 + mt) * 64 + lane) * 8);
        acc[mt] = __builtin_amdgcn_mfma_f32_16x16x32_bf16(af, bf, acc[mt], 0, 0, 0);
      }
    }
#pragma unroll
    for (int mt = 0; mt < 4; ++mt)
#pragma unroll
      for (int reg = 0; reg < 4; ++reg) {
        const int o = (half * 4 + mt) * 16 + quad * 4 + reg;
        qk[((size_t)(b * 128 + o)) * NN + n] = f2bf(acc[mt][reg] + bqkv[o]);
      }
    __builtin_amdgcn_sched_barrier(0);  // keep halves' acc live-ranges disjoint
  }
  // m1 GEMM + BN (64 outputs).
  f32x4 acc2[4];
#pragma unroll
  for (int mt = 0; mt < 4; ++mt) acc2[mt] = (f32x4){0.f, 0.f, 0.f, 0.f};
#pragma unroll
  for (int cc = 0; cc < 2; ++cc) {
    const short8 bf = *(const short8*)(lds + nloc * 66 + cc * 32 + quad * 8);
#pragma unroll
    for (int mt = 0; mt < 4; ++mt) {
      const short8 af = *(const short8*)(apm + ((cc * 4 + mt) * 64 + lane) * 8);
      acc2[mt] = __builtin_amdgcn_mfma_f32_16x16x32_bf16(af, bf, acc2[mt], 0, 0, 0);
    }
  }
  __syncthreads();  // all transpose-buffer reads done; safe to overwrite
#pragma unroll
  for (int mt = 0; mt < 4; ++mt)
#pragma unroll
    for (int reg = 0; reg < 4; ++reg) {
      const int o = mt * 16 + quad * 4 + reg;
      const float sc = gamma[o] * rsqrtf(var[o] + 1e-5f);
      lds[nloc * 66 + o] = f2bf((acc2[mt][reg] - mean[o]) * sc + beta[o]);
    }
  __syncthreads();
  {
    short* dst = y_t + ((size_t)(b * NN + n0)) * 64;
#pragma unroll
    for (int it = 0; it < 2; ++it) {
      const int idx = it * 256 + t;
      const int nl = idx >> 3, cb = idx & 7;
      *(short8*)(dst + (size_t)nl * 64 + cb * 8) = *(const short8*)(lds + nl * 66 + cb * 8);
    }
  }
}

// ---------------------------------------------------------------------------
// K2: FUSED depthwise-3x3 + Gram, register-hoisted rows, single-shfl edges.
// Frozen at round-8 form.
__global__ __launch_bounds__(256, 3) void k_gram(const short* __restrict__ qk,
    const float* __restrict__ wdw, const float* __restrict__ bdw,
    float* __restrict__ gram2) {
  __shared__ float red[4][256];
  const int bh = blockIdx.x >> 6, chunk = blockIdx.x & 63;
  const int b = bh >> 3, h = bh & 7;
  const int wave = threadIdx.x >> 6, lane = threadIdx.x & 63;
  const int quad = lane >> 4, l15 = lane & 15;
  const int ch = (l15 < 8) ? (h * 8 + l15) : (64 + h * 8 + (l15 - 8));
  const short* plane = qk + ((size_t)(b * 128 + ch)) * NN;
  float wreg[9];
#pragma unroll
  for (int i = 0; i < 9; ++i) wreg[i] = wdw[ch * 9 + i];
  const float bias = bdw[ch];
  const int row = chunk * 4 + wave;          // wave-uniform output row 0..255
  const short* prow = plane + row * 256;
  u32x4 rb[3][8];
#pragma unroll
  for (int dy = 0; dy < 3; ++dy) {
    if (dy == 0 && row == 0) continue;       // wave-uniform
    if (dy == 2 && row == 255) continue;
    const short* pr = prow + (dy - 1) * 256 + quad * 8;
#pragma unroll
    for (int s = 0; s < 8; ++s)
      rb[dy][s] = *(const u32x4*)(pr + s * 32);
  }
  f32x4 acc = {0.f, 0.f, 0.f, 0.f};
#pragma unroll
  for (int s = 0; s < 8; ++s) {
    float a[8];
#pragma unroll
    for (int j = 0; j < 8; ++j) a[j] = bias;
#pragma unroll
    for (int dy = 0; dy < 3; ++dy) {
      if (dy == 0 && row == 0) continue;     // wave-uniform (shfls stay full-wave)
      if (dy == 2 && row == 255) continue;
      const unsigned w0_ = rb[dy][s][0], w1_ = rb[dy][s][1],
                     w2_ = rb[dy][s][2], w3_ = rb[dy][s][3];
      float m[10];
      m[1] = lof(w0_); m[2] = hif(w0_);
      m[3] = lof(w1_); m[4] = hif(w1_);
      m[5] = lof(w2_); m[6] = hif(w2_);
      m[7] = lof(w3_); m[8] = hif(w3_);
      unsigned m0w, m9w;
      if (s == 0) {
        m0w = (unsigned)__shfl((int)w3_, (lane - 16) & 63, 64);
      } else {
        const unsigned w3sel = (quad == 3) ? rb[dy][s - 1][3] : w3_;
        m0w = (unsigned)__shfl((int)w3sel, (lane - 16) & 63, 64);
      }
      if (s == 7) {
        m9w = (unsigned)__shfl((int)w0_, (lane + 16) & 63, 64);
      } else {
        const unsigned w0sel = (quad == 0) ? rb[dy][s + 1][0] : w0_;
        m9w = (unsigned)__shfl((int)w0sel, (lane + 16) & 63, 64);
      }
      m[0] = (s == 0 && quad == 0) ? 0.f : hif(m0w);
      m[9] = (s == 7 && quad == 3) ? 0.f : lof(m9w);
      const float W0 = wreg[dy * 3], W1 = wreg[dy * 3 + 1], W2 = wreg[dy * 3 + 2];
#pragma unroll
      for (int j = 0; j < 8; ++j)
        a[j] = fmaf(W2, m[j + 2], fmaf(W1, m[j + 1], fmaf(W0, m[j], a[j])));
    }
    short8 frag;
#pragma unroll
    for (int j = 0; j < 8; ++j) frag[j] = f2bf(a[j]);
    acc = __builtin_amdgcn_mfma_f32_16x16x32_bf16(frag, frag, acc, 0, 0, 0);
  }
#pragma unroll
  for (int reg = 0; reg < 4; ++reg)
    red[wave][(quad * 4 + reg) * 16 + l15] = acc[reg];
  __syncthreads();
  {
    const int e = threadIdx.x;
    const float s4 = red[0][e] + red[1][e] + red[2][e] + red[3][e];
    atomicAdd(&gram2[bh * 256 + e], s4);
  }
}

// ---------------------------------------------------------------------------
// P2+E: blocks 0..63 pack w2 -> apw2 (apw2 aliases dead qk: after k_gram);
// blocks 64..79 do softmax + wproj fold -> Epack.
__global__ __launch_bounds__(256) void k_prep2e(const float* __restrict__ w2,
    short* __restrict__ apw2, const float* __restrict__ gram2,
    const float* __restrict__ temp, const float* __restrict__ wproj,
    short* __restrict__ Epack) {
  if (blockIdx.x < 64) {
    for (int idx = blockIdx.x * 256 + threadIdx.x; idx < 25 * 2 * 4 * 64 * 8; idx += 16384) {
      const int j = idx & 7, lane = (idx >> 3) & 63, mt = (idx >> 9) & 3,
                cc = (idx >> 11) & 1, t = idx >> 12;
      const int o = mt * 16 + (lane & 15);
      const int c = cc * 32 + (lane >> 4) * 8 + j;
      apw2[idx] = f2bf(w2[((size_t)o * 64 + c) * 25 + t]);
    }
    return;
  }
  const int bid = blockIdx.x - 64;  // 0..15
  __shared__ float attn[2048];
  const int t = threadIdx.x;
  {
    const int b = t >> 6, h = (t >> 3) & 7, c = t & 7;
    const float* g = gram2 + (b * 8 + h) * 256;
    const float qn = fmaxf(sqrtf(g[c * 16 + c]), 1e-12f);
    const float tp = temp[h];
    float row[8];
    float mx = -1e30f;
#pragma unroll
    for (int d = 0; d < 8; ++d) {
      const float kn = fmaxf(sqrtf(g[(8 + d) * 16 + (8 + d)]), 1e-12f);
      row[d] = g[c * 16 + 8 + d] / (qn * kn) * tp;
      mx = fmaxf(mx, row[d]);
    }
    float s = 0.f;
#pragma unroll
    for (int d = 0; d < 8; ++d) { row[d] = __expf(row[d] - mx); s += row[d]; }
    const float inv = 1.f / s;
#pragma unroll
    for (int d = 0; d < 8; ++d) attn[t * 8 + d] = row[d] * inv;
  }
  __syncthreads();
  for (int idx = bid * 1024 + t; idx < (bid + 1) * 1024; idx += 256) {
    const int j = idx & 7, lane = (idx >> 3) & 63, mt = (idx >> 9) & 3,
              cc = (idx >> 11) & 1, b = idx >> 12;
    const int o = mt * 16 + (lane & 15);
    const int cv = cc * 32 + (lane >> 4) * 8 + j;
    const int h = cv >> 3, d = cv & 7;
    float a = 0.f;
#pragma unroll
    for (int c2 = 0; c2 < 8; ++c2)
      a += wproj[o * 64 + h * 8 + c2] * attn[((b * 8 + h) * 8 + c2) * 8 + d];
    Epack[idx] = f2bf(a);
  }
}

// ---------------------------------------------------------------------------
// K4: conv5x5 implicit-GEMM MFMA — frozen at the round-6/8 best: 8-ROW TILE
// (512 blocks = 2/CU), two cc phases, XOR-swizzled staging (conflict-free),
// (256,2) -> no spill.
__global__ __launch_bounds__(256, 2) void k_conv5(const short* __restrict__ y_t,
    const short* __restrict__ apw2, const short* __restrict__ x_t,
    short* __restrict__ v_t) {
  __shared__ short slds[8 * 64 * 76];  // 77,824 B >= staging 12*68*64B = 52,224 B
  char* sb = (char*)slds;
  const int b = blockIdx.x >> 7;
  const int rg = (blockIdx.x >> 2) & 31, cg = blockIdx.x & 3;
  const int r0 = rg * 8, x0 = cg * 64;
  const int wave = threadIdx.x >> 6, lane = threadIdx.x & 63;
  const int quad = lane >> 4, l15 = lane & 15;
  f32x4 acc[4][2][4];
#pragma unroll
  for (int mt = 0; mt < 4; ++mt)
#pragma unroll
    for (int r = 0; r < 2; ++r)
#pragma unroll
      for (int nt = 0; nt < 4; ++nt) acc[mt][r][nt] = (f32x4){0.f, 0.f, 0.f, 0.f};
  for (int cc = 0; cc < 2; ++cc) {
    if (cc) __syncthreads();
    for (int idx = threadIdx.x; idx < 12 * 68 * 4; idx += 256) {
      const int rr = idx / 272, rem = idx - rr * 272;
      const int col = rem >> 2, cb = rem & 3;
      const int gr = r0 - 2 + rr, gc = x0 - 2 + col;
      short8 val = {0, 0, 0, 0, 0, 0, 0, 0};
      if (gr >= 0 && gr < 256 && gc >= 0 && gc < 256)
        val = *(const short8*)(y_t + ((size_t)(b * NN + gr * 256 + gc)) * 64 + cc * 32 + cb * 8);
      const int L = rr * 68 + col;
      *(short8*)(sb + ((L * 64 + cb * 16) ^ (((L >> 1) & 3) << 4))) = val;
    }
    __syncthreads();
    for (int t = 0; t < 25; ++t) {
      const int dy = t / 5 - 2, dx = t % 5 - 2;
      short8 a[4];
#pragma unroll
      for (int mt = 0; mt < 4; ++mt)
        a[mt] = *(const short8*)(apw2 + (((t * 2 + cc) * 4 + mt) * 64 + lane) * 8);
#pragma unroll
      for (int r = 0; r < 2; ++r) {
        const int rr = wave * 2 + r + 2 + dy;
#pragma unroll
        for (int nt = 0; nt < 4; ++nt) {
          const int L = rr * 68 + nt * 16 + l15 + 2 + dx;
          const short8 bf =
              *(const short8*)(sb + ((L * 64 + quad * 16) ^ (((L >> 1) & 3) << 4)));
#pragma unroll
          for (int mt = 0; mt < 4; ++mt)
            acc[mt][r][nt] =
                __builtin_amdgcn_mfma_f32_16x16x32_bf16(a[mt], bf, acc[mt][r][nt], 0, 0, 0);
        }
      }
    }
  }
  __syncthreads();  // done reading staging; reuse slds as [row8][col64] stride 76
#pragma unroll
  for (int r = 0; r < 2; ++r) {
    const int lrow = wave * 2 + r;
    const int row = r0 + lrow;
#pragma unroll
    for (int nt = 0; nt < 4; ++nt) {
      const int lcol = nt * 16 + l15;
      const short* xp = x_t + ((size_t)(b * NN + row * 256 + x0 + lcol)) * 64 + quad * 4;
#pragma unroll
      for (int mt = 0; mt < 4; ++mt) {
        const short4b xv4 = *(const short4b*)(xp + mt * 16);
        short4b pk;
#pragma unroll
        for (int reg = 0; reg < 4; ++reg) {
          const float sg = 1.f / (1.f + __expf(-acc[mt][r][nt][reg]));
          pk[reg] = f2bf(bf2f(xv4[reg]) * (1.f + sg));
        }
        *(short4b*)(slds + (lrow * 64 + lcol) * 76 + mt * 16 + quad * 4) = pk;
      }
    }
  }
  __syncthreads();
#pragma unroll
  for (int it = 0; it < 16; ++it) {
    const int idx = it * 256 + threadIdx.x;
    const int cb = idx & 7, lcol = (idx >> 3) & 63, rr = idx >> 9;
    *(short8*)(v_t + ((size_t)(b * NN + (r0 + rr) * 256 + x0 + lcol)) * 64 + cb * 8) =
        *(const short8*)(slds + (rr * 64 + lcol) * 76 + cb * 8);
  }
}

// ---------------------------------------------------------------------------
// K6: out[b,o,n] = bproj[o] + E[b].v_t  as per-batch MFMA GEMM, fp32 stores.
// (256,6): acc is only 16 regs; more waves to hide store latency.
__global__ __launch_bounds__(256, 6) void k_out(const short* __restrict__ v_t,
    const short* __restrict__ Epack, const float* __restrict__ bproj,
    float* __restrict__ out) {
  const int b = blockIdx.x >> 10, ntile = blockIdx.x & 1023;
  const int wave = threadIdx.x >> 6, lane = threadIdx.x & 63;
  const int quad = lane >> 4, l15 = lane & 15;
  const int n = ntile * 64 + wave * 16 + l15;
  f32x4 acc[4];
#pragma unroll
  for (int mt = 0; mt < 4; ++mt) acc[mt] = (f32x4){0.f, 0.f, 0.f, 0.f};
#pragma unroll
  for (int cc = 0; cc < 2; ++cc) {
    const short8 bf = *(const short8*)(v_t + ((size_t)(b * NN + n)) * 64 + cc * 32 + quad * 8);
#pragma unroll
    for (int mt = 0; mt < 4; ++mt) {
      const short8 af = *(const short8*)(Epack + (((b * 2 + cc) * 4 + mt) * 64 + lane) * 8);
      acc[mt] = __builtin_amdgcn_mfma_f32_16x16x32_bf16(af, bf, acc[mt], 0, 0, 0);
    }
  }
#pragma unroll
  for (int mt = 0; mt < 4; ++mt)
#pragma unroll
    for (int reg = 0; reg < 4; ++reg) {
      const int o = mt * 16 + quad * 4 + reg;
      out[((size_t)(b * 64 + o)) * NN + n] = acc[mt][reg] + bproj[o];
    }
}

// ---------------------------------------------------------------------------
// Workspace (byte offsets), total 134307840 <= proven ws capacity:
//  [0,   64M)  qk bf16 [b][128][N]  -> after k_gram: v_t [0,32M), apw2 @32M
//  [64M, 96M)  x_t bf16 [b][n][64]
//  [96M,128M)  y_t bf16 [b][n][64]
//  [128M, ..)  gram2 32KB | apk 16KB | apm 8KB | Epack 32KB
extern "C" void kernel_launch(void* const* d_in, const int* in_sizes, int n_in,
                              void* d_out, int out_size, void* d_ws, size_t ws_size,
                              hipStream_t stream) {
  const float* x     = (const float*)d_in[0];
  const float* wqkv  = (const float*)d_in[1];
  const float* bqkv  = (const float*)d_in[2];
  const float* wdw   = (const float*)d_in[3];
  const float* bdw   = (const float*)d_in[4];
  const float* wproj = (const float*)d_in[5];
  const float* bproj = (const float*)d_in[6];
  const float* temp  = (const float*)d_in[7];
  const float* wm1   = (const float*)d_in[8];
  const float* gamma = (const float*)d_in[9];
  const float* beta  = (const float*)d_in[10];
  const float* mean  = (const float*)d_in[11];
  const float* var   = (const float*)d_in[12];
  const float* wm2   = (const float*)d_in[13];

  char* wsb = (char*)d_ws;
  short* qk    = (short*)(wsb);
  short* v_t   = (short*)(wsb);                       // aliases qk (after k_gram)
  short* apw2  = (short*)(wsb + 33554432);            // aliases qk tail (after k_gram)
  short* x_t   = (short*)(wsb + 67108864);
  short* y_t   = (short*)(wsb + 100663296);
  float* gram2 = (float*)(wsb + 134217728);
  short* apk   = (short*)(wsb + 134217728 + 32768);
  short* apm   = (short*)(wsb + 134217728 + 49152);
  short* Epack = (short*)(wsb + 134217728 + 57344);
  float* out   = (float*)d_out;

  k_prep1<<<dim3(64), dim3(256), 0, stream>>>(wqkv, wm1, apk, apm, gram2);
  k_fused<<<dim3(4096), dim3(256), 0, stream>>>(x, apk, bqkv, apm, gamma, beta,
                                                mean, var, x_t, qk, y_t);
  k_gram<<<dim3(2048), dim3(256), 0, stream>>>(qk, wdw, bdw, gram2);
  k_prep2e<<<dim3(80), dim3(256), 0, stream>>>(wm2, apw2, gram2, temp, wproj, Epack);
  k_conv5<<<dim3(512), dim3(256), 0, stream>>>(y_t, apw2, x_t, v_t);
  k_out<<<dim3(4096), dim3(256), 0, stream>>>(v_t, Epack, bproj, out);
}